// Round 2
// baseline (693.368 us; speedup 1.0000x reference)
//
#include <hip/hip_runtime.h>
#include <cstdint>

#define THREADS 256
static constexpr int BS   = 4096;
static constexpr int C    = 16384;
static constexpr int D    = 128;
static constexpr int HALF = 2048;   // rows 0..2047 pair with rows 2048..4095
static constexpr int NPOS = 4;
static constexpr int NNEG = 20;
static constexpr int NSEL = 24;
static constexpr int QPT  = 16;     // int4 quads per thread (16*4 = 64 cols)

// ---- JAX threefry2x32 (20 rounds), key = PRNGKey(42) = [0, 42] ----
__device__ __forceinline__ void tf2x32(uint32_t x0, uint32_t x1,
                                       uint32_t& o0, uint32_t& o1) {
  constexpr uint32_t ks0 = 0u, ks1 = 42u;
  constexpr uint32_t ks2 = 0x1BD11BDAu ^ ks0 ^ ks1;
  x0 += ks0; x1 += ks1;
#define TFR(r) { x0 += x1; x1 = (x1 << (r)) | (x1 >> (32 - (r))); x1 ^= x0; }
  TFR(13) TFR(15) TFR(26) TFR(6)
  x0 += ks1; x1 += ks2 + 1u;
  TFR(17) TFR(29) TFR(16) TFR(24)
  x0 += ks2; x1 += ks0 + 2u;
  TFR(13) TFR(15) TFR(26) TFR(6)
  x0 += ks0; x1 += ks1 + 3u;
  TFR(17) TFR(29) TFR(16) TFR(24)
  x0 += ks1; x1 += ks2 + 4u;
  TFR(13) TFR(15) TFR(26) TFR(6)
  x0 += ks2; x1 += ks0 + 5u;
#undef TFR
  o0 = x0; o1 = x1;
}

// composite key: (bits23+1) << 14 | (16383-col). Larger = better;
// equal bits -> smaller col wins (matches jax.lax.top_k tie-break).
__device__ __forceinline__ uint64_t mkcomp(uint32_t bits, int c) {
  return (((uint64_t)(bits >> 9) + 1ull) << 14) | (uint64_t)(16383 - c);
}

__device__ __forceinline__ void ins4(uint64_t v, uint64_t& a, uint64_t& b,
                                     uint64_t& c, uint64_t& d) {
  if (v > d) {
    if (v > b) {
      if (v > a) { d = c; c = b; b = a; a = v; }
      else       { d = c; c = b; b = v; }
    } else {
      if (v > c) { d = c; c = v; }
      else       { d = v; }
    }
  }
}

// COLD path: a thread's cached top-4 is exhausted (needs >=5 of the row's
// top-20 from one thread; P ~ 1.5e-2 over the whole grid). Re-scan its 64
// columns excluding positives (labels) and all already-selected cols.
__device__ __attribute__((noinline)) uint64_t rebuild_thread(
    const int* __restrict__ lab, int rowg, int rbase, int hi, int thr,
    const int* selX, int nsel) {
  uint64_t b0 = 0;
  const int4* l4 = reinterpret_cast<const int4*>(lab + (size_t)rowg * C);
  for (int j = 0; j < QPT; ++j) {
    const int q = j * THREADS + thr;
    const int4 lv = l4[q];
#pragma unroll
    for (int i = 0; i < 4; ++i) {
      const int lvi = (i == 0) ? lv.x : (i == 1) ? lv.y : (i == 2) ? lv.z : lv.w;
      if (lvi) continue;
      const int c = (q << 2) + i;
      bool skip = false;
      for (int k = 0; k < nsel; ++k) skip = skip || (selX[k] == c);
      if (skip) continue;
      uint32_t o0, o1;
      tf2x32((uint32_t)(rbase + c), (uint32_t)(rbase + c) + 0x2000000u, o0, o1);
      const uint64_t v = mkcomp(hi ? o1 : o0, c);
      if (v > b0) b0 = v;
    }
  }
  return b0;
}

// Wave-synchronous top-20 selection for one row. Executed by one full wave,
// no block barriers. Each lane owns 4 threads' top-4 candidate lists.
__device__ __forceinline__ void wave_select(
    const uint64_t (*cand)[5], int* selX,
    const int* __restrict__ lab, int rowg, int rbase, int hi) {
  const int lane = threadIdx.x & 63;
  const int tb = lane << 2;
  const uint64_t laneu = (uint64_t)lane;
  uint64_t c0 = cand[tb + 0][0], c1 = cand[tb + 1][0],
           c2 = cand[tb + 2][0], c3 = cand[tb + 3][0];
  int i0 = 0, i1 = 0, i2 = 0, i3 = 0;
  uint64_t tg0 = (c0 << 8) | (0ull << 6) | laneu;
  uint64_t tg1 = (c1 << 8) | (1ull << 6) | laneu;
  uint64_t tg2 = (c2 << 8) | (2ull << 6) | laneu;
  uint64_t tg3 = (c3 << 8) | (3ull << 6) | laneu;
  for (int it = 0; it < NNEG; ++it) {
    uint64_t m = tg0;
    if (tg1 > m) m = tg1;
    if (tg2 > m) m = tg2;
    if (tg3 > m) m = tg3;
#pragma unroll
    for (int o = 32; o; o >>= 1) {
      const uint64_t y = (uint64_t)__shfl_xor((unsigned long long)m, o, 64);
      if (y > m) m = y;
    }
    if (lane == 0) selX[NPOS + it] = 16383 - (int)((m >> 8) & 0x3FFFull);
    __threadfence_block();   // selX write visible before any rebuild reads it
    if (lane == (int)(m & 63ull)) {
      const int s = (int)((m >> 6) & 3ull);
      if (s == 0) {
        c0 = (++i0 < 4) ? cand[tb + 0][i0]
                        : rebuild_thread(lab, rowg, rbase, hi, tb + 0, selX, NPOS + it + 1);
        tg0 = (c0 << 8) | (0ull << 6) | laneu;
      } else if (s == 1) {
        c1 = (++i1 < 4) ? cand[tb + 1][i1]
                        : rebuild_thread(lab, rowg, rbase, hi, tb + 1, selX, NPOS + it + 1);
        tg1 = (c1 << 8) | (1ull << 6) | laneu;
      } else if (s == 2) {
        c2 = (++i2 < 4) ? cand[tb + 2][i2]
                        : rebuild_thread(lab, rowg, rbase, hi, tb + 2, selX, NPOS + it + 1);
        tg2 = (c2 << 8) | (2ull << 6) | laneu;
      } else {
        c3 = (++i3 < 4) ? cand[tb + 3][i3]
                        : rebuild_thread(lab, rowg, rbase, hi, tb + 3, selX, NPOS + it + 1);
        tg3 = (c3 << 8) | (3ull << 6) | laneu;
      }
    }
  }
}

__global__ __launch_bounds__(THREADS, 4) void supcon_main(
    const float* __restrict__ feat, const float* __restrict__ proto,
    const int* __restrict__ lab, float* __restrict__ row_ws) {
  __shared__ uint64_t candL[THREADS][5];   // [5]: +1 u64 pad vs bank conflicts
  __shared__ uint64_t candH[THREADS][5];
  __shared__ int selL[NSEL], selH[NSEL];
  __shared__ int posCnt[2];
  __shared__ int posBuf[2][4];
  __shared__ float ffL[D], ffH[D];
  __shared__ float normL, normH;
  __shared__ float bces[2 * NSEL];

  const int tid = threadIdx.x;
  const int r = blockIdx.x;            // low row; pairs with r+HALF
  const int rbase = r * C;             // also the threefry x0 base (< 2^25)

  if (tid < 2) posCnt[tid] = 0;
  __syncthreads();

  // ---- Phase A: stream labels, hash, per-thread top-4 per row ----
  uint64_t L0 = 0, L1 = 0, L2 = 0, L3 = 0, H0 = 0, H1 = 0, H2 = 0, H3 = 0;
  const int4* labL4 = reinterpret_cast<const int4*>(lab + (size_t)rbase);
  const int4* labH4 = reinterpret_cast<const int4*>(lab + ((size_t)r + HALF) * C);

  for (int j = 0; j < QPT; ++j) {
    const int q = j * THREADS + tid;
    const int4 lL = labL4[q];
    const int4 lH = labH4[q];
    const int c0 = q << 2;
    uint32_t o0, o1;
#define DOCOL(i, LX, HX) {                                                     \
    const int c = c0 + (i);                                                    \
    tf2x32((uint32_t)(rbase + c), (uint32_t)(rbase + c) + 0x2000000u, o0, o1); \
    if (LX) { int s = atomicAdd(&posCnt[0], 1); if (s < 4) posBuf[0][s] = c; } \
    else ins4(mkcomp(o0, c), L0, L1, L2, L3);                                  \
    if (HX) { int s = atomicAdd(&posCnt[1], 1); if (s < 4) posBuf[1][s] = c; } \
    else ins4(mkcomp(o1, c), H0, H1, H2, H3); }
    DOCOL(0, lL.x, lH.x)
    DOCOL(1, lL.y, lH.y)
    DOCOL(2, lL.z, lH.z)
    DOCOL(3, lL.w, lH.w)
#undef DOCOL
  }
  candL[tid][0] = L0; candL[tid][1] = L1; candL[tid][2] = L2; candL[tid][3] = L3;
  candH[tid][0] = H0; candH[tid][1] = H1; candH[tid][2] = H2; candH[tid][3] = H3;
  __syncthreads();

  if (tid < 2) {   // sort the 4 positive cols ascending (jax top_k tie order)
    int a = posBuf[tid][0], b = posBuf[tid][1], c2 = posBuf[tid][2], d = posBuf[tid][3];
#define CSW(x, y) if (x > y) { int t_ = x; x = y; y = t_; }
    CSW(a, b) CSW(c2, d) CSW(a, c2) CSW(b, d) CSW(b, c2)
#undef CSW
    int* s = tid ? selH : selL;
    s[0] = a; s[1] = b; s[2] = c2; s[3] = d;
  }
  __syncthreads();

  // ---- Phase B: wave 0 selects L negs, wave 1 selects H negs,
  //      waves 2/3 load + normalize the two feature rows. No barriers inside.
  const int wv = tid >> 6;
  if (wv == 0) {
    wave_select(candL, selL, lab, r, rbase, 0);
  } else if (wv == 1) {
    wave_select(candH, selH, lab, r + HALF, rbase, 1);
  } else if (wv == 2) {
    const int l = tid & 63;
    const float a = feat[(size_t)r * D + l];
    const float b = feat[(size_t)r * D + 64 + l];
    ffL[l] = a; ffL[64 + l] = b;
    float s = a * a + b * b;
#pragma unroll
    for (int o = 32; o; o >>= 1) s += __shfl_xor(s, o, 64);
    if (l == 0) normL = s;
  } else {
    const int l = tid & 63;
    const float a = feat[((size_t)r + HALF) * D + l];
    const float b = feat[((size_t)r + HALF) * D + 64 + l];
    ffH[l] = a; ffH[64 + l] = b;
    float s = a * a + b * b;
#pragma unroll
    for (int o = 32; o; o >>= 1) s += __shfl_xor(s, o, 64);
    if (l == 0) normH = s;
  }
  __syncthreads();

  // ---- Phase C: 48 selected columns x 4 lanes each -> sim + BCE ----
  if (tid < 4 * 2 * NSEL) {
    const int ci = tid >> 2;            // 0..47
    const int k  = tid & 3;
    const bool isH = ci >= NSEL;
    const int g = isH ? ci - NSEL : ci;
    const int c = isH ? selH[g] : selL[g];
    const float* ff = isH ? ffH : ffL;
    const float4* pc = reinterpret_cast<const float4*>(proto + (size_t)c * D);
    float fp = 0.f, pp = 0.f;
#pragma unroll
    for (int qq = 0; qq < 8; ++qq) {
      const float4 pv = pc[k * 8 + qq];
      const int d0 = k * 32 + qq * 4;
      fp += ff[d0] * pv.x + ff[d0 + 1] * pv.y + ff[d0 + 2] * pv.z + ff[d0 + 3] * pv.w;
      pp += pv.x * pv.x + pv.y * pv.y + pv.z * pv.z + pv.w * pv.w;
    }
    fp += __shfl_xor(fp, 1, 64); pp += __shfl_xor(pp, 1, 64);
    fp += __shfl_xor(fp, 2, 64); pp += __shfl_xor(pp, 2, 64);
    if (k == 0) {
      const float x = (isH ? normH : normL) * pp;
      float rn = rsqrtf(x);
      rn = rn * (1.5f - 0.5f * x * rn * rn);   // 1 NR step for accuracy
      const float l = fp * rn * 10.0f;          // /TEMP, TEMP=0.1
      const float tgt = (g < NPOS) ? 0.25f : 0.0f;
      bces[ci] = fmaxf(l, 0.f) - l * tgt + log1pf(expf(-fabsf(l)));
    }
  }
  __syncthreads();
  if (tid < 2) {
    float s = 0.f;
    const int base = tid * NSEL;
#pragma unroll
    for (int i = 0; i < NSEL; ++i) s += bces[base + i];
    row_ws[tid ? (r + HALF) : r] = s * (1.0f / NSEL);
  }
}

__global__ __launch_bounds__(THREADS) void supcon_reduce(
    const float* __restrict__ ws, float* __restrict__ out) {
  __shared__ float red[THREADS];
  const int tid = threadIdx.x;
  float s = 0.f;
#pragma unroll
  for (int j = 0; j < BS / THREADS; ++j) s += ws[j * THREADS + tid];
  red[tid] = s;
  __syncthreads();
  for (int o = THREADS / 2; o > 0; o >>= 1) {
    if (tid < o) red[tid] += red[tid + o];
    __syncthreads();
  }
  if (tid == 0) out[0] = red[0] * (1.0f / BS);
}

extern "C" void kernel_launch(void* const* d_in, const int* in_sizes, int n_in,
                              void* d_out, int out_size, void* d_ws, size_t ws_size,
                              hipStream_t stream) {
  (void)in_sizes; (void)n_in; (void)out_size; (void)ws_size;
  const float* feat  = (const float*)d_in[0];
  const float* proto = (const float*)d_in[1];
  const int*   lab   = (const int*)d_in[2];
  float* out = (float*)d_out;
  float* ws  = (float*)d_ws;   // 4096 per-row mean-BCE values

  supcon_main<<<dim3(HALF), dim3(THREADS), 0, stream>>>(feat, proto, lab, ws);
  supcon_reduce<<<dim3(1), dim3(THREADS), 0, stream>>>(ws, out);
}

// Round 3
// 625.434 us; speedup vs baseline: 1.1086x; 1.1086x over previous
//
#include <hip/hip_runtime.h>
#include <cstdint>

#define THREADS 256
static constexpr int BS   = 4096;
static constexpr int C    = 16384;
static constexpr int D    = 128;
static constexpr int HALF = 2048;   // rows 0..2047 pair with rows 2048..4095
static constexpr int NPOS = 4;
static constexpr int NNEG = 20;
static constexpr int NSEL = 24;
static constexpr int QPT  = 16;     // int4 quads per thread (16*4 = 64 cols)

// ---- JAX threefry2x32 (20 rounds), key = PRNGKey(42) = [0, 42] ----
__device__ __forceinline__ void tf2x32(uint32_t x0, uint32_t x1,
                                       uint32_t& o0, uint32_t& o1) {
  constexpr uint32_t ks0 = 0u, ks1 = 42u;
  constexpr uint32_t ks2 = 0x1BD11BDAu ^ ks0 ^ ks1;
  x0 += ks0; x1 += ks1;
#define TFR(r) { x0 += x1; x1 = (x1 << (r)) | (x1 >> (32 - (r))); x1 ^= x0; }
  TFR(13) TFR(15) TFR(26) TFR(6)
  x0 += ks1; x1 += ks2 + 1u;
  TFR(17) TFR(29) TFR(16) TFR(24)
  x0 += ks2; x1 += ks0 + 2u;
  TFR(13) TFR(15) TFR(26) TFR(6)
  x0 += ks0; x1 += ks1 + 3u;
  TFR(17) TFR(29) TFR(16) TFR(24)
  x0 += ks1; x1 += ks2 + 4u;
  TFR(13) TFR(15) TFR(26) TFR(6)
  x0 += ks2; x1 += ks0 + 5u;
#undef TFR
  o0 = x0; o1 = x1;
}

// composite key: (bits23+1) << 14 | (16383-col). Larger = better; equal bits
// -> smaller col wins (matches jax.lax.top_k tie-break). Unique per row
// (col in low bits). 0 is the "no candidate" sentinel.
__device__ __forceinline__ uint64_t mkcomp(uint32_t bits, int c) {
  return (((uint64_t)(bits >> 9) + 1ull) << 14) | (uint64_t)(16383 - c);
}

__device__ __forceinline__ void ins4(uint64_t v, uint64_t& a, uint64_t& b,
                                     uint64_t& c, uint64_t& d) {
  if (v > d) {
    if (v > b) {
      if (v > a) { d = c; c = b; b = a; a = v; }
      else       { d = c; c = b; b = v; }
    } else {
      if (v > c) { d = c; c = v; }
      else       { d = v; }
    }
  }
}

// COLD path (P ~ 1.5e-2 over the entire problem): thread `thr`'s cached top-4
// is exhausted; its next candidate is its best comp STRICTLY BELOW `bound`
// (the last value consumed from this thread). Comps are unique, so no
// exclusion list is needed. Positives (label==1) are skipped.
__device__ __forceinline__ uint64_t rebuild_next(
    const int* __restrict__ lab_row, int rbase, int hi, int thr, uint64_t bound) {
  uint64_t b = 0;
  for (int j = 0; j < QPT; ++j) {
    const int q = j * THREADS + thr;
#pragma unroll
    for (int i = 0; i < 4; ++i) {
      const int c = (q << 2) + i;
      if (lab_row[c]) continue;
      uint32_t o0, o1;
      tf2x32((uint32_t)(rbase + c), (uint32_t)(rbase + c) + 0x2000000u, o0, o1);
      const uint64_t v = mkcomp(hi ? o1 : o0, c);
      if (v < bound && v > b) b = v;
    }
  }
  return b;
}

// Wave-synchronous top-20 selection for one row: one full wave, zero block
// barriers. Each lane owns 4 threads' cached top-4 lists (in LDS).
__device__ __forceinline__ void wave_select(
    const uint64_t (*cand)[4], int* selX,
    const int* __restrict__ lab_row, int rbase, int hi) {
  const int lane = threadIdx.x & 63;
  const int tb = lane << 2;
  const uint64_t laneu = (uint64_t)lane;
  uint64_t c0 = cand[tb + 0][0], c1 = cand[tb + 1][0],
           c2 = cand[tb + 2][0], c3 = cand[tb + 3][0];
  int i0 = 0, i1 = 0, i2 = 0, i3 = 0;
  for (int it = 0; it < NNEG; ++it) {
    uint64_t m = (c0 << 8) | laneu;
    uint64_t t = (c1 << 8) | (1ull << 6) | laneu; if (t > m) m = t;
    t = (c2 << 8) | (2ull << 6) | laneu;          if (t > m) m = t;
    t = (c3 << 8) | (3ull << 6) | laneu;          if (t > m) m = t;
#pragma unroll
    for (int o = 32; o; o >>= 1) {
      const uint64_t y = (uint64_t)__shfl_xor((unsigned long long)m, o, 64);
      if (y > m) m = y;
    }
    if (lane == 0) selX[NPOS + it] = 16383 - (int)((m >> 8) & 0x3FFFull);
    if (lane == (int)(m & 63ull)) {
      const int s = (int)((m >> 6) & 3ull);
      if (s == 0) {
        const uint64_t b = c0;
        c0 = (++i0 < 4) ? cand[tb + 0][i0] : rebuild_next(lab_row, rbase, hi, tb + 0, b);
      } else if (s == 1) {
        const uint64_t b = c1;
        c1 = (++i1 < 4) ? cand[tb + 1][i1] : rebuild_next(lab_row, rbase, hi, tb + 1, b);
      } else if (s == 2) {
        const uint64_t b = c2;
        c2 = (++i2 < 4) ? cand[tb + 2][i2] : rebuild_next(lab_row, rbase, hi, tb + 2, b);
      } else {
        const uint64_t b = c3;
        c3 = (++i3 < 4) ? cand[tb + 3][i3] : rebuild_next(lab_row, rbase, hi, tb + 3, b);
      }
    }
  }
}

__global__ __launch_bounds__(THREADS, 4) void supcon_main(
    const float* __restrict__ feat, const float* __restrict__ proto,
    const int* __restrict__ lab, float* __restrict__ row_ws) {
  __shared__ uint64_t candL[THREADS][4];
  __shared__ uint64_t candH[THREADS][4];
  __shared__ int selL[NSEL], selH[NSEL];
  __shared__ int posCnt[2];
  __shared__ int posBuf[2][4];
  __shared__ float ffL[D], ffH[D];
  __shared__ float normL, normH;
  __shared__ float bces[2 * NSEL];

  const int tid = threadIdx.x;
  const int r = blockIdx.x;            // low row; pairs with r+HALF
  const int rbase = r * C;             // threefry x0 base (< 2^25)

  if (tid < 2) posCnt[tid] = 0;
  __syncthreads();

  // ---- Phase A: stream labels, hash, per-thread top-4 per row ----
  uint64_t L0 = 0, L1 = 0, L2 = 0, L3 = 0, H0 = 0, H1 = 0, H2 = 0, H3 = 0;
  const int4* labL4 = reinterpret_cast<const int4*>(lab + (size_t)rbase);
  const int4* labH4 = reinterpret_cast<const int4*>(lab + ((size_t)r + HALF) * C);

  for (int j = 0; j < QPT; ++j) {
    const int q = j * THREADS + tid;
    const int4 lL = labL4[q];
    const int4 lH = labH4[q];
    const int c0 = q << 2;
    uint32_t o0, o1;
#define DOCOL(i, LX, HX) {                                                     \
    const int c = c0 + (i);                                                    \
    tf2x32((uint32_t)(rbase + c), (uint32_t)(rbase + c) + 0x2000000u, o0, o1); \
    if (LX) { int s = atomicAdd(&posCnt[0], 1); if (s < 4) posBuf[0][s] = c; } \
    else ins4(mkcomp(o0, c), L0, L1, L2, L3);                                  \
    if (HX) { int s = atomicAdd(&posCnt[1], 1); if (s < 4) posBuf[1][s] = c; } \
    else ins4(mkcomp(o1, c), H0, H1, H2, H3); }
    DOCOL(0, lL.x, lH.x)
    DOCOL(1, lL.y, lH.y)
    DOCOL(2, lL.z, lH.z)
    DOCOL(3, lL.w, lH.w)
#undef DOCOL
  }
  candL[tid][0] = L0; candL[tid][1] = L1; candL[tid][2] = L2; candL[tid][3] = L3;
  candH[tid][0] = H0; candH[tid][1] = H1; candH[tid][2] = H2; candH[tid][3] = H3;
  __syncthreads();

  if (tid < 2) {   // sort the 4 positive cols ascending (jax top_k tie order)
    int a = posBuf[tid][0], b = posBuf[tid][1], c2 = posBuf[tid][2], d = posBuf[tid][3];
#define CSW(x, y) if (x > y) { int t_ = x; x = y; y = t_; }
    CSW(a, b) CSW(c2, d) CSW(a, c2) CSW(b, d) CSW(b, c2)
#undef CSW
    int* s = tid ? selH : selL;
    s[0] = a; s[1] = b; s[2] = c2; s[3] = d;
  }
  __syncthreads();

  // ---- Phase B: wave 0 selects L negs, wave 1 selects H negs,
  //      waves 2/3 load + normalize the two feature rows. No barriers inside.
  const int wv = tid >> 6;
  if (wv == 0) {
    wave_select(candL, selL, lab + (size_t)rbase, rbase, 0);
  } else if (wv == 1) {
    wave_select(candH, selH, lab + ((size_t)r + HALF) * C, rbase, 1);
  } else if (wv == 2) {
    const int l = tid & 63;
    const float a = feat[(size_t)r * D + l];
    const float b = feat[(size_t)r * D + 64 + l];
    ffL[l] = a; ffL[64 + l] = b;
    float s = a * a + b * b;
#pragma unroll
    for (int o = 32; o; o >>= 1) s += __shfl_xor(s, o, 64);
    if (l == 0) normL = s;
  } else {
    const int l = tid & 63;
    const float a = feat[((size_t)r + HALF) * D + l];
    const float b = feat[((size_t)r + HALF) * D + 64 + l];
    ffH[l] = a; ffH[64 + l] = b;
    float s = a * a + b * b;
#pragma unroll
    for (int o = 32; o; o >>= 1) s += __shfl_xor(s, o, 64);
    if (l == 0) normH = s;
  }
  __syncthreads();

  // ---- Phase C: 48 selected columns x 4 lanes each -> sim + BCE ----
  if (tid < 4 * 2 * NSEL) {
    const int ci = tid >> 2;            // 0..47
    const int k  = tid & 3;
    const bool isH = ci >= NSEL;
    const int g = isH ? ci - NSEL : ci;
    const int c = isH ? selH[g] : selL[g];
    const float* ff = isH ? ffH : ffL;
    const float4* pc = reinterpret_cast<const float4*>(proto + (size_t)c * D);
    float fp = 0.f, pp = 0.f;
#pragma unroll
    for (int qq = 0; qq < 8; ++qq) {
      const float4 pv = pc[k * 8 + qq];
      const int d0 = k * 32 + qq * 4;
      fp += ff[d0] * pv.x + ff[d0 + 1] * pv.y + ff[d0 + 2] * pv.z + ff[d0 + 3] * pv.w;
      pp += pv.x * pv.x + pv.y * pv.y + pv.z * pv.z + pv.w * pv.w;
    }
    fp += __shfl_xor(fp, 1, 64); pp += __shfl_xor(pp, 1, 64);
    fp += __shfl_xor(fp, 2, 64); pp += __shfl_xor(pp, 2, 64);
    if (k == 0) {
      const float x = (isH ? normH : normL) * pp;
      float rn = rsqrtf(x);
      rn = rn * (1.5f - 0.5f * x * rn * rn);   // 1 NR step for accuracy
      const float l = fp * rn * 10.0f;          // /TEMP, TEMP=0.1
      const float tgt = (g < NPOS) ? 0.25f : 0.0f;
      bces[ci] = fmaxf(l, 0.f) - l * tgt + __logf(1.0f + __expf(-fabsf(l)));
    }
  }
  __syncthreads();
  if (tid < 2) {
    float s = 0.f;
    const int base = tid * NSEL;
#pragma unroll
    for (int i = 0; i < NSEL; ++i) s += bces[base + i];
    row_ws[tid ? (r + HALF) : r] = s * (1.0f / NSEL);
  }
}

__global__ __launch_bounds__(THREADS) void supcon_reduce(
    const float* __restrict__ ws, float* __restrict__ out) {
  __shared__ float red[THREADS];
  const int tid = threadIdx.x;
  float s = 0.f;
#pragma unroll
  for (int j = 0; j < BS / THREADS; ++j) s += ws[j * THREADS + tid];
  red[tid] = s;
  __syncthreads();
  for (int o = THREADS / 2; o > 0; o >>= 1) {
    if (tid < o) red[tid] += red[tid + o];
    __syncthreads();
  }
  if (tid == 0) out[0] = red[0] * (1.0f / BS);
}

extern "C" void kernel_launch(void* const* d_in, const int* in_sizes, int n_in,
                              void* d_out, int out_size, void* d_ws, size_t ws_size,
                              hipStream_t stream) {
  (void)in_sizes; (void)n_in; (void)out_size; (void)ws_size;
  const float* feat  = (const float*)d_in[0];
  const float* proto = (const float*)d_in[1];
  const int*   lab   = (const int*)d_in[2];
  float* out = (float*)d_out;
  float* ws  = (float*)d_ws;   // 4096 per-row mean-BCE values

  supcon_main<<<dim3(HALF), dim3(THREADS), 0, stream>>>(feat, proto, lab, ws);
  supcon_reduce<<<dim3(1), dim3(THREADS), 0, stream>>>(ws, out);
}

// Round 4
// 477.204 us; speedup vs baseline: 1.4530x; 1.3106x over previous
//
#include <hip/hip_runtime.h>
#include <cstdint>

#define THREADS 256
static constexpr int BS   = 4096;
static constexpr int C    = 16384;
static constexpr int D    = 128;
static constexpr int HALF = 2048;   // rows 0..2047 pair with rows 2048..4095
static constexpr int NPOS = 4;
static constexpr int NNEG = 20;
static constexpr int NSEL = 24;
static constexpr int QPT  = 16;     // int4 quads per thread (16*4 = 64 cols)

// ---- JAX threefry2x32 (20 rounds), key = PRNGKey(42) = [0, 42] ----
__device__ __forceinline__ void tf2x32(uint32_t x0, uint32_t x1,
                                       uint32_t& o0, uint32_t& o1) {
  constexpr uint32_t ks0 = 0u, ks1 = 42u;
  constexpr uint32_t ks2 = 0x1BD11BDAu ^ ks0 ^ ks1;
  x0 += ks0; x1 += ks1;
#define TFR(r) { x0 += x1; x1 = (x1 << (r)) | (x1 >> (32 - (r))); x1 ^= x0; }
  TFR(13) TFR(15) TFR(26) TFR(6)
  x0 += ks1; x1 += ks2 + 1u;
  TFR(17) TFR(29) TFR(16) TFR(24)
  x0 += ks2; x1 += ks0 + 2u;
  TFR(13) TFR(15) TFR(26) TFR(6)
  x0 += ks0; x1 += ks1 + 3u;
  TFR(17) TFR(29) TFR(16) TFR(24)
  x0 += ks1; x1 += ks2 + 4u;
  TFR(13) TFR(15) TFR(26) TFR(6)
  x0 += ks2; x1 += ks0 + 5u;
#undef TFR
  o0 = x0; o1 = x1;
}

// composite key: (bits23+1) << 14 | (16383-col). Larger = better; equal bits
// -> smaller col wins (matches jax.lax.top_k tie-break). Unique per row.
__device__ __forceinline__ uint64_t mkcomp(uint32_t bits, int c) {
  return (((uint64_t)(bits >> 9) + 1ull) << 14) | (uint64_t)(16383 - c);
}

__device__ __forceinline__ void ins4(uint64_t v, uint64_t& a, uint64_t& b,
                                     uint64_t& c, uint64_t& d) {
  if (v > d) {
    if (v > b) {
      if (v > a) { d = c; c = b; b = a; a = v; }
      else       { d = c; c = b; b = v; }
    } else {
      if (v > c) { d = c; c = v; }
      else       { d = v; }
    }
  }
}

// ---------- kernel 0: labels (multi-hot, 256 MB) -> pos_idx[row][4] ----------
__global__ __launch_bounds__(THREADS) void pos_extract(
    const int* __restrict__ lab, int* __restrict__ posIdx) {
  __shared__ int cnt;
  __shared__ int buf[8];
  const int row = blockIdx.x;
  const int tid = threadIdx.x;
  if (tid == 0) cnt = 0;
  __syncthreads();
  const int4* l4 = reinterpret_cast<const int4*>(lab + (size_t)row * C);
  for (int j = 0; j < QPT; ++j) {
    const int q = j * THREADS + tid;
    const int4 v = l4[q];
    if (v.x | v.y | v.z | v.w) {      // rare: <=4 threads per block enter
      const int c0 = q << 2;
      if (v.x) { int s = atomicAdd(&cnt, 1); if (s < 8) buf[s] = c0; }
      if (v.y) { int s = atomicAdd(&cnt, 1); if (s < 8) buf[s] = c0 + 1; }
      if (v.z) { int s = atomicAdd(&cnt, 1); if (s < 8) buf[s] = c0 + 2; }
      if (v.w) { int s = atomicAdd(&cnt, 1); if (s < 8) buf[s] = c0 + 3; }
    }
  }
  __syncthreads();
  if (tid == 0) {   // exactly 4 positives; sort ascending (jax top_k tie order)
    int a = buf[0], b = buf[1], c = buf[2], d = buf[3];
#define CSW(x, y) if (x > y) { int t_ = x; x = y; y = t_; }
    CSW(a, b) CSW(c, d) CSW(a, c) CSW(b, d) CSW(b, c)
#undef CSW
    int4 o; o.x = a; o.y = b; o.z = c; o.w = d;
    *reinterpret_cast<int4*>(posIdx + (size_t)row * 4) = o;
  }
}

// COLD path (expected ~dozens of occurrences across the whole grid): thread
// `thr`'s cached top-4 is exhausted; next candidate = best comp STRICTLY BELOW
// `bound`. Comps are unique per row, so no exclusion list needed.
__device__ __forceinline__ uint64_t rebuild_next(
    int rbase, int hi, int thr, uint64_t bound, int4 p) {
  uint64_t b = 0;
  for (int j = 0; j < QPT; ++j) {
    const int q = j * THREADS + thr;
#pragma unroll
    for (int i = 0; i < 4; ++i) {
      const int c = (q << 2) + i;
      if (c == p.x || c == p.y || c == p.z || c == p.w) continue;
      uint32_t o0, o1;
      tf2x32((uint32_t)(rbase + c), (uint32_t)(rbase + c) + 0x2000000u, o0, o1);
      const uint64_t v = mkcomp(hi ? o1 : o0, c);
      if (v < bound && v > b) b = v;
    }
  }
  return b;
}

// Wave-synchronous top-20 selection for one row: one full wave, zero block
// barriers, no memory traffic except LDS. Each lane owns 4 threads' top-4.
__device__ __forceinline__ void wave_select(
    const uint64_t (*cand)[4], int* selX, int rbase, int hi, int4 p) {
  const int lane = threadIdx.x & 63;
  const int tb = lane << 2;
  const uint64_t laneu = (uint64_t)lane;
  uint64_t c0 = cand[tb + 0][0], c1 = cand[tb + 1][0],
           c2 = cand[tb + 2][0], c3 = cand[tb + 3][0];
  int i0 = 0, i1 = 0, i2 = 0, i3 = 0;
  for (int it = 0; it < NNEG; ++it) {
    uint64_t m = (c0 << 8) | laneu;
    uint64_t t = (c1 << 8) | (1ull << 6) | laneu; if (t > m) m = t;
    t = (c2 << 8) | (2ull << 6) | laneu;          if (t > m) m = t;
    t = (c3 << 8) | (3ull << 6) | laneu;          if (t > m) m = t;
#pragma unroll
    for (int o = 32; o; o >>= 1) {
      const uint64_t y = (uint64_t)__shfl_xor((unsigned long long)m, o, 64);
      if (y > m) m = y;
    }
    if (lane == 0) selX[NPOS + it] = 16383 - (int)((m >> 8) & 0x3FFFull);
    if (lane == (int)(m & 63ull)) {
      const int s = (int)((m >> 6) & 3ull);
      if (s == 0) {
        const uint64_t b = c0;
        c0 = (++i0 < 4) ? cand[tb + 0][i0] : rebuild_next(rbase, hi, tb + 0, b, p);
      } else if (s == 1) {
        const uint64_t b = c1;
        c1 = (++i1 < 4) ? cand[tb + 1][i1] : rebuild_next(rbase, hi, tb + 1, b, p);
      } else if (s == 2) {
        const uint64_t b = c2;
        c2 = (++i2 < 4) ? cand[tb + 2][i2] : rebuild_next(rbase, hi, tb + 2, b, p);
      } else {
        const uint64_t b = c3;
        c3 = (++i3 < 4) ? cand[tb + 3][i3] : rebuild_next(rbase, hi, tb + 3, b, p);
      }
    }
  }
}

// ---------- kernel 1: hash + select + sim + BCE (no label reads) ----------
__global__ __launch_bounds__(THREADS) void supcon_main(
    const float* __restrict__ feat, const float* __restrict__ proto,
    const int* __restrict__ posIdx, float* __restrict__ row_ws) {
  __shared__ uint64_t candL[THREADS][4];
  __shared__ uint64_t candH[THREADS][4];
  __shared__ int selL[NSEL], selH[NSEL];
  __shared__ float ffL[D], ffH[D];
  __shared__ float normL, normH;
  __shared__ float bces[2 * NSEL];

  const int tid = threadIdx.x;
  const int r = blockIdx.x;            // low row; pairs with r+HALF
  const int rbase = r * C;             // threefry x0 base (< 2^25)

  // block-uniform addresses -> scalar loads -> SGPRs
  const int4 pL = *reinterpret_cast<const int4*>(posIdx + (size_t)r * 4);
  const int4 pH = *reinterpret_cast<const int4*>(posIdx + ((size_t)r + HALF) * 4);

  // ---- Phase A: pure-VALU hash + per-thread top-4 per row ----
  uint64_t L0 = 0, L1 = 0, L2 = 0, L3 = 0, H0 = 0, H1 = 0, H2 = 0, H3 = 0;
  for (int j = 0; j < QPT; ++j) {
    const int c0 = (j * THREADS + tid) << 2;
#pragma unroll
    for (int i = 0; i < 4; ++i) {
      const int c = c0 + i;
      uint32_t o0, o1;
      tf2x32((uint32_t)(rbase + c), (uint32_t)(rbase + c) + 0x2000000u, o0, o1);
      if (c != pL.x && c != pL.y && c != pL.z && c != pL.w)
        ins4(mkcomp(o0, c), L0, L1, L2, L3);
      if (c != pH.x && c != pH.y && c != pH.z && c != pH.w)
        ins4(mkcomp(o1, c), H0, H1, H2, H3);
    }
  }
  candL[tid][0] = L0; candL[tid][1] = L1; candL[tid][2] = L2; candL[tid][3] = L3;
  candH[tid][0] = H0; candH[tid][1] = H1; candH[tid][2] = H2; candH[tid][3] = H3;
  if (tid == 0) { selL[0] = pL.x; selL[1] = pL.y; selL[2] = pL.z; selL[3] = pL.w; }
  if (tid == 1) { selH[0] = pH.x; selH[1] = pH.y; selH[2] = pH.z; selH[3] = pH.w; }
  __syncthreads();

  // ---- Phase B: wave 0 selects L negs, wave 1 selects H negs,
  //      waves 2/3 load + normalize the two feature rows. No barriers inside.
  const int wv = tid >> 6;
  if (wv == 0) {
    wave_select(candL, selL, rbase, 0, pL);
  } else if (wv == 1) {
    wave_select(candH, selH, rbase, 1, pH);
  } else if (wv == 2) {
    const int l = tid & 63;
    const float a = feat[(size_t)r * D + l];
    const float b = feat[(size_t)r * D + 64 + l];
    ffL[l] = a; ffL[64 + l] = b;
    float s = a * a + b * b;
#pragma unroll
    for (int o = 32; o; o >>= 1) s += __shfl_xor(s, o, 64);
    if (l == 0) normL = s;
  } else {
    const int l = tid & 63;
    const float a = feat[((size_t)r + HALF) * D + l];
    const float b = feat[((size_t)r + HALF) * D + 64 + l];
    ffH[l] = a; ffH[64 + l] = b;
    float s = a * a + b * b;
#pragma unroll
    for (int o = 32; o; o >>= 1) s += __shfl_xor(s, o, 64);
    if (l == 0) normH = s;
  }
  __syncthreads();

  // ---- Phase C: 48 selected columns x 4 lanes each -> sim + BCE ----
  if (tid < 4 * 2 * NSEL) {
    const int ci = tid >> 2;            // 0..47
    const int k  = tid & 3;
    const bool isH = ci >= NSEL;
    const int g = isH ? ci - NSEL : ci;
    const int c = isH ? selH[g] : selL[g];
    const float* ff = isH ? ffH : ffL;
    const float4* pc = reinterpret_cast<const float4*>(proto + (size_t)c * D);
    float fp = 0.f, pp = 0.f;
#pragma unroll
    for (int qq = 0; qq < 8; ++qq) {
      const float4 pv = pc[k * 8 + qq];
      const int d0 = k * 32 + qq * 4;
      fp += ff[d0] * pv.x + ff[d0 + 1] * pv.y + ff[d0 + 2] * pv.z + ff[d0 + 3] * pv.w;
      pp += pv.x * pv.x + pv.y * pv.y + pv.z * pv.z + pv.w * pv.w;
    }
    fp += __shfl_xor(fp, 1, 64); pp += __shfl_xor(pp, 1, 64);
    fp += __shfl_xor(fp, 2, 64); pp += __shfl_xor(pp, 2, 64);
    if (k == 0) {
      const float x = (isH ? normH : normL) * pp;
      float rn = rsqrtf(x);
      rn = rn * (1.5f - 0.5f * x * rn * rn);   // 1 NR step for accuracy
      const float l = fp * rn * 10.0f;          // /TEMP, TEMP=0.1
      const float tgt = (g < NPOS) ? 0.25f : 0.0f;
      bces[ci] = fmaxf(l, 0.f) - l * tgt + __logf(1.0f + __expf(-fabsf(l)));
    }
  }
  __syncthreads();
  if (tid < 2) {
    float s = 0.f;
    const int base = tid * NSEL;
#pragma unroll
    for (int i = 0; i < NSEL; ++i) s += bces[base + i];
    row_ws[tid ? (r + HALF) : r] = s * (1.0f / NSEL);
  }
}

__global__ __launch_bounds__(THREADS) void supcon_reduce(
    const float* __restrict__ ws, float* __restrict__ out) {
  __shared__ float red[THREADS];
  const int tid = threadIdx.x;
  float s = 0.f;
#pragma unroll
  for (int j = 0; j < BS / THREADS; ++j) s += ws[j * THREADS + tid];
  red[tid] = s;
  __syncthreads();
  for (int o = THREADS / 2; o > 0; o >>= 1) {
    if (tid < o) red[tid] += red[tid + o];
    __syncthreads();
  }
  if (tid == 0) out[0] = red[0] * (1.0f / BS);
}

extern "C" void kernel_launch(void* const* d_in, const int* in_sizes, int n_in,
                              void* d_out, int out_size, void* d_ws, size_t ws_size,
                              hipStream_t stream) {
  (void)in_sizes; (void)n_in; (void)out_size; (void)ws_size;
  const float* feat  = (const float*)d_in[0];
  const float* proto = (const float*)d_in[1];
  const int*   lab   = (const int*)d_in[2];
  float* out = (float*)d_out;
  float* ws  = (float*)d_ws;                      // [0..4095]: per-row BCE
  int*   posIdx = (int*)((char*)d_ws + BS * sizeof(float));  // [4096][4]

  pos_extract<<<dim3(BS),   dim3(THREADS), 0, stream>>>(lab, posIdx);
  supcon_main<<<dim3(HALF), dim3(THREADS), 0, stream>>>(feat, proto, posIdx, ws);
  supcon_reduce<<<dim3(1),  dim3(THREADS), 0, stream>>>(ws, out);
}

// Round 5
// 175.753 us; speedup vs baseline: 3.9451x; 2.7152x over previous
//
#include <hip/hip_runtime.h>
#include <cstdint>

#define THREADS 256
static constexpr int BS   = 4096;
static constexpr int C    = 16384;
static constexpr int D    = 128;
static constexpr int HALF = 2048;   // rows 0..2047 pair with rows 2048..4095
static constexpr int NPOS = 4;
static constexpr int NNEG = 20;
static constexpr int NSEL = 24;
static constexpr int QPT  = 16;     // int4 quads per thread (16*4 = 64 cols)

// ---- JAX threefry2x32 (20 rounds), key = PRNGKey(42) = [0, 42] ----
__device__ __forceinline__ void tf2x32(uint32_t x0, uint32_t x1,
                                       uint32_t& o0, uint32_t& o1) {
  constexpr uint32_t ks0 = 0u, ks1 = 42u;
  constexpr uint32_t ks2 = 0x1BD11BDAu ^ ks0 ^ ks1;
  x0 += ks0; x1 += ks1;
#define TFR(r) { x0 += x1; x1 = (x1 << (r)) | (x1 >> (32 - (r))); x1 ^= x0; }
  TFR(13) TFR(15) TFR(26) TFR(6)
  x0 += ks1; x1 += ks2 + 1u;
  TFR(17) TFR(29) TFR(16) TFR(24)
  x0 += ks2; x1 += ks0 + 2u;
  TFR(13) TFR(15) TFR(26) TFR(6)
  x0 += ks0; x1 += ks1 + 3u;
  TFR(17) TFR(29) TFR(16) TFR(24)
  x0 += ks1; x1 += ks2 + 4u;
  TFR(13) TFR(15) TFR(26) TFR(6)
  x0 += ks2; x1 += ks0 + 5u;
#undef TFR
  o0 = x0; o1 = x1;
}

// composite key: (bits23+1) << 14 | (16383-col). Larger = better; equal bits
// -> smaller col wins (matches jax.lax.top_k tie-break). Unique per row.
// 0 is the "empty" sentinel (real comps are >= 1<<14).
__device__ __forceinline__ uint64_t mkcomp(uint32_t bits, int c) {
  return (((uint64_t)(bits >> 9) + 1ull) << 14) | (uint64_t)(16383 - c);
}

// branchless top-2 insert (a >= b invariant)
__device__ __forceinline__ void ins2(uint64_t v, uint64_t& a, uint64_t& b) {
  const uint64_t lo = v < a ? v : a;
  a = v > a ? v : a;
  b = lo > b ? lo : b;
}

// ---------- kernel 0: labels (multi-hot, 256 MB) -> pos_idx[row][4] ----------
__global__ __launch_bounds__(THREADS) void pos_extract(
    const int* __restrict__ lab, int* __restrict__ posIdx) {
  __shared__ int cnt;
  __shared__ int buf[8];
  const int row = blockIdx.x;
  const int tid = threadIdx.x;
  if (tid == 0) cnt = 0;
  __syncthreads();
  const int4* l4 = reinterpret_cast<const int4*>(lab + (size_t)row * C);
  for (int j = 0; j < QPT; ++j) {
    const int q = j * THREADS + tid;
    const int4 v = l4[q];
    if (v.x | v.y | v.z | v.w) {      // rare: <=4 threads per block enter
      const int c0 = q << 2;
      if (v.x) { int s = atomicAdd(&cnt, 1); if (s < 8) buf[s] = c0; }
      if (v.y) { int s = atomicAdd(&cnt, 1); if (s < 8) buf[s] = c0 + 1; }
      if (v.z) { int s = atomicAdd(&cnt, 1); if (s < 8) buf[s] = c0 + 2; }
      if (v.w) { int s = atomicAdd(&cnt, 1); if (s < 8) buf[s] = c0 + 3; }
    }
  }
  __syncthreads();
  if (tid == 0) {   // exactly 4 positives; sort ascending (jax top_k tie order)
    int a = buf[0], b = buf[1], c = buf[2], d = buf[3];
#define CSW(x, y) if (x > y) { int t_ = x; x = y; y = t_; }
    CSW(a, b) CSW(c, d) CSW(a, c) CSW(b, d) CSW(b, c)
#undef CSW
    int4 o; o.x = a; o.y = b; o.z = c; o.w = d;
    *reinterpret_cast<int4*>(posIdx + (size_t)row * 4) = o;
  }
}

// Wave-synchronous top-20 selection for one row: one full wave, zero block
// barriers. Lane owns threads tb..tb+3; each thread contributes a depth-2
// register-cached candidate list. When a thread's cache is exhausted, ALL 64
// lanes cooperatively rescan its 64 columns (1 hash per lane + 6-step shfl
// max) for its next candidate strictly below the last consumed value.
__device__ __forceinline__ void wave_select(
    const uint64_t (*cand)[2], int* selX, int rbase, int hi, int4 p) {
  const int lane = threadIdx.x & 63;
  const int tb = lane << 2;
  const uint64_t laneu = (uint64_t)lane;
  uint64_t cur0 = cand[tb + 0][0], nxt0 = cand[tb + 0][1];
  uint64_t cur1 = cand[tb + 1][0], nxt1 = cand[tb + 1][1];
  uint64_t cur2 = cand[tb + 2][0], nxt2 = cand[tb + 2][1];
  uint64_t cur3 = cand[tb + 3][0], nxt3 = cand[tb + 3][1];
  for (int it = 0; it < NNEG; ++it) {
    uint64_t m = (cur0 << 8) | laneu;
    uint64_t t = (cur1 << 8) | 0x40ull | laneu; if (t > m) m = t;
    t = (cur2 << 8) | 0x80ull | laneu;          if (t > m) m = t;
    t = (cur3 << 8) | 0xC0ull | laneu;          if (t > m) m = t;
#pragma unroll
    for (int o = 32; o; o >>= 1) {
      const uint64_t y = (uint64_t)__shfl_xor((unsigned long long)m, o, 64);
      if (y > m) m = y;
    }
    if (lane == 0) selX[NPOS + it] = 16383 - (int)((m >> 8) & 0x3FFFull);
    const int owner = (int)(m & 63ull);
    const int slot  = (int)((m >> 6) & 3ull);
    const uint64_t bound = m >> 8;
    const uint64_t mynxt = slot == 0 ? nxt0 : slot == 1 ? nxt1
                         : slot == 2 ? nxt2 : nxt3;
    const uint64_t ownnxt =
        (uint64_t)__shfl((unsigned long long)mynxt, owner, 64);
    if (ownnxt) {                       // wave-uniform branch
      if (lane == owner) {
        if      (slot == 0) { cur0 = ownnxt; nxt0 = 0; }
        else if (slot == 1) { cur1 = ownnxt; nxt1 = 0; }
        else if (slot == 2) { cur2 = ownnxt; nxt2 = 0; }
        else                { cur3 = ownnxt; nxt3 = 0; }
      }
    } else {                            // cooperative rebuild (rare)
      const int thr = (owner << 2) | slot;
      const int col = (((lane >> 2) * THREADS + thr) << 2) + (lane & 3);
      uint32_t o0, o1;
      tf2x32((uint32_t)(rbase + col), (uint32_t)(rbase + col) + 0x2000000u, o0, o1);
      uint64_t v = mkcomp(hi ? o1 : o0, col);
      if (col == p.x || col == p.y || col == p.z || col == p.w || v >= bound)
        v = 0;
#pragma unroll
      for (int o = 32; o; o >>= 1) {
        const uint64_t y = (uint64_t)__shfl_xor((unsigned long long)v, o, 64);
        if (y > v) v = y;
      }
      if (lane == owner) {
        if      (slot == 0) cur0 = v;
        else if (slot == 1) cur1 = v;
        else if (slot == 2) cur2 = v;
        else                cur3 = v;
      }
    }
  }
}

// ---------- kernel 1: hash + select + sim + BCE (no label reads) ----------
__global__ __launch_bounds__(THREADS, 2) void supcon_main(
    const float* __restrict__ feat, const float* __restrict__ proto,
    const int* __restrict__ posIdx, float* __restrict__ row_ws) {
  __shared__ uint64_t candL[THREADS][2];
  __shared__ uint64_t candH[THREADS][2];
  __shared__ int selL[NSEL], selH[NSEL];
  __shared__ float ffL[D], ffH[D];
  __shared__ float normL, normH;
  __shared__ float bces[2 * NSEL];

  const int tid = threadIdx.x;
  const int r = blockIdx.x;            // low row; pairs with r+HALF
  const int rbase = r * C;             // threefry x0 base (< 2^25)

  const int4 pL = *reinterpret_cast<const int4*>(posIdx + (size_t)r * 4);
  const int4 pH = *reinterpret_cast<const int4*>(posIdx + ((size_t)r + HALF) * 4);

  // ---- Phase A: pure-VALU hash + per-thread top-2 per row (4 live u64) ----
  uint64_t L0 = 0, L1 = 0, H0 = 0, H1 = 0;
  for (int j = 0; j < QPT; ++j) {
    const int c0 = (j * THREADS + tid) << 2;
#pragma unroll
    for (int i = 0; i < 4; ++i) {
      const int c = c0 + i;
      uint32_t o0, o1;
      tf2x32((uint32_t)(rbase + c), (uint32_t)(rbase + c) + 0x2000000u, o0, o1);
      if (c != pL.x && c != pL.y && c != pL.z && c != pL.w)
        ins2(mkcomp(o0, c), L0, L1);
      if (c != pH.x && c != pH.y && c != pH.z && c != pH.w)
        ins2(mkcomp(o1, c), H0, H1);
    }
  }
  candL[tid][0] = L0; candL[tid][1] = L1;
  candH[tid][0] = H0; candH[tid][1] = H1;
  if (tid == 0) { selL[0] = pL.x; selL[1] = pL.y; selL[2] = pL.z; selL[3] = pL.w; }
  if (tid == 1) { selH[0] = pH.x; selH[1] = pH.y; selH[2] = pH.z; selH[3] = pH.w; }
  __syncthreads();

  // ---- Phase B: wave 0 selects L negs, wave 1 selects H negs,
  //      waves 2/3 load + normalize the two feature rows. No barriers inside.
  const int wv = tid >> 6;
  if (wv == 0) {
    wave_select(candL, selL, rbase, 0, pL);
  } else if (wv == 1) {
    wave_select(candH, selH, rbase, 1, pH);
  } else if (wv == 2) {
    const int l = tid & 63;
    const float a = feat[(size_t)r * D + l];
    const float b = feat[(size_t)r * D + 64 + l];
    ffL[l] = a; ffL[64 + l] = b;
    float s = a * a + b * b;
#pragma unroll
    for (int o = 32; o; o >>= 1) s += __shfl_xor(s, o, 64);
    if (l == 0) normL = s;
  } else {
    const int l = tid & 63;
    const float a = feat[((size_t)r + HALF) * D + l];
    const float b = feat[((size_t)r + HALF) * D + 64 + l];
    ffH[l] = a; ffH[64 + l] = b;
    float s = a * a + b * b;
#pragma unroll
    for (int o = 32; o; o >>= 1) s += __shfl_xor(s, o, 64);
    if (l == 0) normH = s;
  }
  __syncthreads();

  // ---- Phase C: 48 selected columns x 4 lanes each -> sim + BCE ----
  if (tid < 4 * 2 * NSEL) {
    const int ci = tid >> 2;            // 0..47
    const int k  = tid & 3;
    const bool isH = ci >= NSEL;
    const int g = isH ? ci - NSEL : ci;
    const int c = isH ? selH[g] : selL[g];
    const float* ff = isH ? ffH : ffL;
    const float4* pc = reinterpret_cast<const float4*>(proto + (size_t)c * D);
    float fp = 0.f, pp = 0.f;
#pragma unroll
    for (int qq = 0; qq < 8; ++qq) {
      const float4 pv = pc[k * 8 + qq];
      const int d0 = k * 32 + qq * 4;
      fp += ff[d0] * pv.x + ff[d0 + 1] * pv.y + ff[d0 + 2] * pv.z + ff[d0 + 3] * pv.w;
      pp += pv.x * pv.x + pv.y * pv.y + pv.z * pv.z + pv.w * pv.w;
    }
    fp += __shfl_xor(fp, 1, 64); pp += __shfl_xor(pp, 1, 64);
    fp += __shfl_xor(fp, 2, 64); pp += __shfl_xor(pp, 2, 64);
    if (k == 0) {
      const float x = (isH ? normH : normL) * pp;
      float rn = rsqrtf(x);
      rn = rn * (1.5f - 0.5f * x * rn * rn);   // 1 NR step for accuracy
      const float l = fp * rn * 10.0f;          // /TEMP, TEMP=0.1
      const float tgt = (g < NPOS) ? 0.25f : 0.0f;
      bces[ci] = fmaxf(l, 0.f) - l * tgt + __logf(1.0f + __expf(-fabsf(l)));
    }
  }
  __syncthreads();
  if (tid < 2) {
    float s = 0.f;
    const int base = tid * NSEL;
#pragma unroll
    for (int i = 0; i < NSEL; ++i) s += bces[base + i];
    row_ws[tid ? (r + HALF) : r] = s * (1.0f / NSEL);
  }
}

__global__ __launch_bounds__(THREADS) void supcon_reduce(
    const float* __restrict__ ws, float* __restrict__ out) {
  __shared__ float red[THREADS];
  const int tid = threadIdx.x;
  float s = 0.f;
#pragma unroll
  for (int j = 0; j < BS / THREADS; ++j) s += ws[j * THREADS + tid];
  red[tid] = s;
  __syncthreads();
  for (int o = THREADS / 2; o > 0; o >>= 1) {
    if (tid < o) red[tid] += red[tid + o];
    __syncthreads();
  }
  if (tid == 0) out[0] = red[0] * (1.0f / BS);
}

extern "C" void kernel_launch(void* const* d_in, const int* in_sizes, int n_in,
                              void* d_out, int out_size, void* d_ws, size_t ws_size,
                              hipStream_t stream) {
  (void)in_sizes; (void)n_in; (void)out_size; (void)ws_size;
  const float* feat  = (const float*)d_in[0];
  const float* proto = (const float*)d_in[1];
  const int*   lab   = (const int*)d_in[2];
  float* out = (float*)d_out;
  float* ws  = (float*)d_ws;                      // [0..4095]: per-row BCE
  int*   posIdx = (int*)((char*)d_ws + BS * sizeof(float));  // [4096][4]

  pos_extract<<<dim3(BS),   dim3(THREADS), 0, stream>>>(lab, posIdx);
  supcon_main<<<dim3(HALF), dim3(THREADS), 0, stream>>>(feat, proto, posIdx, ws);
  supcon_reduce<<<dim3(1),  dim3(THREADS), 0, stream>>>(ws, out);
}

// Round 6
// 131.697 us; speedup vs baseline: 5.2649x; 1.3345x over previous
//
#include <hip/hip_runtime.h>
#include <cstdint>

#define THREADS 256
static constexpr int BS   = 4096;
static constexpr int C    = 16384;
static constexpr int D    = 128;
static constexpr int HALF = 2048;   // rows 0..2047 pair with rows 2048..4095
static constexpr int NPOS = 4;
static constexpr int NNEG = 20;
static constexpr int NSEL = 24;
static constexpr int QPT  = 16;     // int4 quads per thread (16*4 = 64 cols)

// Pre-filter: only comps with raw bits >= TH enter the per-thread top-2.
// Top 1/128 of u32 -> expected ~128 above-thresh negatives per row (need 20;
// P(shortfall) ~ e^-73). Selection stays EXACT regardless: the cooperative
// rebuild recomputes a thread's next candidate with no threshold.
static constexpr uint32_t TH = 0xFE000000u;

// ---- JAX threefry2x32 (20 rounds), key = PRNGKey(42) = [0, 42] ----
__device__ __forceinline__ void tf2x32(uint32_t x0, uint32_t x1,
                                       uint32_t& o0, uint32_t& o1) {
  constexpr uint32_t ks0 = 0u, ks1 = 42u;
  constexpr uint32_t ks2 = 0x1BD11BDAu ^ ks0 ^ ks1;
  x0 += ks0; x1 += ks1;
#define TFR(r) { x0 += x1; x1 = (x1 << (r)) | (x1 >> (32 - (r))); x1 ^= x0; }
  TFR(13) TFR(15) TFR(26) TFR(6)
  x0 += ks1; x1 += ks2 + 1u;
  TFR(17) TFR(29) TFR(16) TFR(24)
  x0 += ks2; x1 += ks0 + 2u;
  TFR(13) TFR(15) TFR(26) TFR(6)
  x0 += ks0; x1 += ks1 + 3u;
  TFR(17) TFR(29) TFR(16) TFR(24)
  x0 += ks1; x1 += ks2 + 4u;
  TFR(13) TFR(15) TFR(26) TFR(6)
  x0 += ks2; x1 += ks0 + 5u;
#undef TFR
  o0 = x0; o1 = x1;
}

// composite key: (bits23+1) << 14 | (16383-col). Larger = better; equal bits
// -> smaller col wins (matches jax.lax.top_k tie-break). Unique per row.
// 0 is the "empty" sentinel (real comps are >= 1<<14).
__device__ __forceinline__ uint64_t mkcomp(uint32_t bits, int c) {
  return (((uint64_t)(bits >> 9) + 1ull) << 14) | (uint64_t)(16383 - c);
}

// branchless top-2 insert (a >= b invariant)
__device__ __forceinline__ void ins2(uint64_t v, uint64_t& a, uint64_t& b) {
  const uint64_t lo = v < a ? v : a;
  a = v > a ? v : a;
  b = lo > b ? lo : b;
}

// Wave-synchronous top-20 selection for one row: one full wave, zero block
// barriers. Lane owns threads tb..tb+3; each thread contributes a depth-2
// register-cached candidate list (top-2 above TH). When a thread's cache is
// exhausted, ALL 64 lanes cooperatively rescan its 64 columns (1 hash per
// lane + 6-step shfl max, NO threshold) for its next candidate strictly
// below the last consumed value.
__device__ __forceinline__ void wave_select(
    const uint64_t (*cand)[2], int* selX, int rbase, int hi, int4 p) {
  const int lane = threadIdx.x & 63;
  const int tb = lane << 2;
  const uint64_t laneu = (uint64_t)lane;
  uint64_t cur0 = cand[tb + 0][0], nxt0 = cand[tb + 0][1];
  uint64_t cur1 = cand[tb + 1][0], nxt1 = cand[tb + 1][1];
  uint64_t cur2 = cand[tb + 2][0], nxt2 = cand[tb + 2][1];
  uint64_t cur3 = cand[tb + 3][0], nxt3 = cand[tb + 3][1];
  for (int it = 0; it < NNEG; ++it) {
    uint64_t m = (cur0 << 8) | laneu;
    uint64_t t = (cur1 << 8) | 0x40ull | laneu; if (t > m) m = t;
    t = (cur2 << 8) | 0x80ull | laneu;          if (t > m) m = t;
    t = (cur3 << 8) | 0xC0ull | laneu;          if (t > m) m = t;
#pragma unroll
    for (int o = 32; o; o >>= 1) {
      const uint64_t y = (uint64_t)__shfl_xor((unsigned long long)m, o, 64);
      if (y > m) m = y;
    }
    if (lane == 0) selX[NPOS + it] = 16383 - (int)((m >> 8) & 0x3FFFull);
    const int owner = (int)(m & 63ull);
    const int slot  = (int)((m >> 6) & 3ull);
    const uint64_t bound = m >> 8;
    const uint64_t mynxt = slot == 0 ? nxt0 : slot == 1 ? nxt1
                         : slot == 2 ? nxt2 : nxt3;
    const uint64_t ownnxt =
        (uint64_t)__shfl((unsigned long long)mynxt, owner, 64);
    if (ownnxt) {                       // wave-uniform branch
      if (lane == owner) {
        if      (slot == 0) { cur0 = ownnxt; nxt0 = 0; }
        else if (slot == 1) { cur1 = ownnxt; nxt1 = 0; }
        else if (slot == 2) { cur2 = ownnxt; nxt2 = 0; }
        else                { cur3 = ownnxt; nxt3 = 0; }
      }
    } else {                            // cooperative rebuild (rare)
      const int thr = (owner << 2) | slot;
      const int col = (((lane >> 2) * THREADS + thr) << 2) + (lane & 3);
      uint32_t o0, o1;
      tf2x32((uint32_t)(rbase + col), (uint32_t)(rbase + col) + 0x2000000u, o0, o1);
      uint64_t v = mkcomp(hi ? o1 : o0, col);
      if (col == p.x || col == p.y || col == p.z || col == p.w || v >= bound)
        v = 0;
#pragma unroll
      for (int o = 32; o; o >>= 1) {
        const uint64_t y = (uint64_t)__shfl_xor((unsigned long long)v, o, 64);
        if (y > v) v = y;
      }
      if (lane == owner) {
        if      (slot == 0) cur0 = v;
        else if (slot == 1) cur1 = v;
        else if (slot == 2) cur2 = v;
        else                cur3 = v;
      }
    }
  }
}

// ---- single fused kernel: stream labels + hash + select + sim + BCE ----
__global__ __launch_bounds__(THREADS, 2) void supcon_fused(
    const float* __restrict__ feat, const float* __restrict__ proto,
    const int* __restrict__ lab, float* __restrict__ row_ws) {
  __shared__ uint64_t candL[THREADS][2];
  __shared__ uint64_t candH[THREADS][2];
  __shared__ int selL[NSEL], selH[NSEL];
  __shared__ int posCnt[2];
  __shared__ int posBuf[2][4];
  __shared__ float ffL[D], ffH[D];
  __shared__ float normL, normH;
  __shared__ float bces[2 * NSEL];

  const int tid = threadIdx.x;
  const int r = blockIdx.x;            // low row; pairs with r+HALF
  const int rbase = r * C;             // threefry x0 base (< 2^25)

  if (tid < 2) posCnt[tid] = 0;
  __syncthreads();

  // ---- Phase A: stream both label rows (prefetched), hash, thresholded
  //      per-thread top-2 per row (4 live u64) ----
  const int4* labL4 = reinterpret_cast<const int4*>(lab + (size_t)rbase);
  const int4* labH4 = reinterpret_cast<const int4*>(lab + ((size_t)r + HALF) * C);
  uint64_t L0 = 0, L1 = 0, H0 = 0, H1 = 0;
  int4 lL = labL4[tid];
  int4 lH = labH4[tid];
  for (int j = 0; j < QPT; ++j) {
    int4 nL, nH;
    if (j + 1 < QPT) {                  // prefetch next quad pair
      nL = labL4[(j + 1) * THREADS + tid];
      nH = labH4[(j + 1) * THREADS + tid];
    }
    const int c0 = (j * THREADS + tid) << 2;
    uint32_t o0, o1;
#define DOCOL(i, LX, HX) {                                                     \
    const int c = c0 + (i);                                                    \
    tf2x32((uint32_t)(rbase + c), (uint32_t)(rbase + c) + 0x2000000u, o0, o1); \
    if (LX) { int s = atomicAdd(&posCnt[0], 1); if (s < 4) posBuf[0][s] = c; } \
    else if (o0 >= TH) ins2(mkcomp(o0, c), L0, L1);                            \
    if (HX) { int s = atomicAdd(&posCnt[1], 1); if (s < 4) posBuf[1][s] = c; } \
    else if (o1 >= TH) ins2(mkcomp(o1, c), H0, H1); }
    DOCOL(0, lL.x, lH.x)
    DOCOL(1, lL.y, lH.y)
    DOCOL(2, lL.z, lH.z)
    DOCOL(3, lL.w, lH.w)
#undef DOCOL
    lL = nL; lH = nH;
  }
  candL[tid][0] = L0; candL[tid][1] = L1;
  candH[tid][0] = H0; candH[tid][1] = H1;
  __syncthreads();

  if (tid < 2) {   // sort the 4 positive cols ascending (jax top_k tie order)
    int a = posBuf[tid][0], b = posBuf[tid][1], c2 = posBuf[tid][2], d = posBuf[tid][3];
#define CSW(x, y) if (x > y) { int t_ = x; x = y; y = t_; }
    CSW(a, b) CSW(c2, d) CSW(a, c2) CSW(b, d) CSW(b, c2)
#undef CSW
    int* s = tid ? selH : selL;
    s[0] = a; s[1] = b; s[2] = c2; s[3] = d;
  }
  __syncthreads();

  // ---- Phase B: wave 0 selects L negs, wave 1 selects H negs,
  //      waves 2/3 load + normalize the two feature rows. No barriers inside.
  const int wv = tid >> 6;
  if (wv == 0) {
    const int4 p = { selL[0], selL[1], selL[2], selL[3] };
    wave_select(candL, selL, rbase, 0, p);
  } else if (wv == 1) {
    const int4 p = { selH[0], selH[1], selH[2], selH[3] };
    wave_select(candH, selH, rbase, 1, p);
  } else if (wv == 2) {
    const int l = tid & 63;
    const float a = feat[(size_t)r * D + l];
    const float b = feat[(size_t)r * D + 64 + l];
    ffL[l] = a; ffL[64 + l] = b;
    float s = a * a + b * b;
#pragma unroll
    for (int o = 32; o; o >>= 1) s += __shfl_xor(s, o, 64);
    if (l == 0) normL = s;
  } else {
    const int l = tid & 63;
    const float a = feat[((size_t)r + HALF) * D + l];
    const float b = feat[((size_t)r + HALF) * D + 64 + l];
    ffH[l] = a; ffH[64 + l] = b;
    float s = a * a + b * b;
#pragma unroll
    for (int o = 32; o; o >>= 1) s += __shfl_xor(s, o, 64);
    if (l == 0) normH = s;
  }
  __syncthreads();

  // ---- Phase C: 48 selected columns x 4 lanes each -> sim + BCE ----
  if (tid < 4 * 2 * NSEL) {
    const int ci = tid >> 2;            // 0..47
    const int k  = tid & 3;
    const bool isH = ci >= NSEL;
    const int g = isH ? ci - NSEL : ci;
    const int c = isH ? selH[g] : selL[g];
    const float* ff = isH ? ffH : ffL;
    const float4* pc = reinterpret_cast<const float4*>(proto + (size_t)c * D);
    float fp = 0.f, pp = 0.f;
#pragma unroll
    for (int qq = 0; qq < 8; ++qq) {
      const float4 pv = pc[k * 8 + qq];
      const int d0 = k * 32 + qq * 4;
      fp += ff[d0] * pv.x + ff[d0 + 1] * pv.y + ff[d0 + 2] * pv.z + ff[d0 + 3] * pv.w;
      pp += pv.x * pv.x + pv.y * pv.y + pv.z * pv.z + pv.w * pv.w;
    }
    fp += __shfl_xor(fp, 1, 64); pp += __shfl_xor(pp, 1, 64);
    fp += __shfl_xor(fp, 2, 64); pp += __shfl_xor(pp, 2, 64);
    if (k == 0) {
      const float x = (isH ? normH : normL) * pp;
      float rn = rsqrtf(x);
      rn = rn * (1.5f - 0.5f * x * rn * rn);   // 1 NR step for accuracy
      const float l = fp * rn * 10.0f;          // /TEMP, TEMP=0.1
      const float tgt = (g < NPOS) ? 0.25f : 0.0f;
      bces[ci] = fmaxf(l, 0.f) - l * tgt + __logf(1.0f + __expf(-fabsf(l)));
    }
  }
  __syncthreads();
  if (tid < 2) {
    float s = 0.f;
    const int base = tid * NSEL;
#pragma unroll
    for (int i = 0; i < NSEL; ++i) s += bces[base + i];
    row_ws[tid ? (r + HALF) : r] = s * (1.0f / NSEL);
  }
}

__global__ __launch_bounds__(THREADS) void supcon_reduce(
    const float* __restrict__ ws, float* __restrict__ out) {
  __shared__ float red[THREADS];
  const int tid = threadIdx.x;
  float s = 0.f;
#pragma unroll
  for (int j = 0; j < BS / THREADS; ++j) s += ws[j * THREADS + tid];
  red[tid] = s;
  __syncthreads();
  for (int o = THREADS / 2; o > 0; o >>= 1) {
    if (tid < o) red[tid] += red[tid + o];
    __syncthreads();
  }
  if (tid == 0) out[0] = red[0] * (1.0f / BS);
}

extern "C" void kernel_launch(void* const* d_in, const int* in_sizes, int n_in,
                              void* d_out, int out_size, void* d_ws, size_t ws_size,
                              hipStream_t stream) {
  (void)in_sizes; (void)n_in; (void)out_size; (void)ws_size;
  const float* feat  = (const float*)d_in[0];
  const float* proto = (const float*)d_in[1];
  const int*   lab   = (const int*)d_in[2];
  float* out = (float*)d_out;
  float* ws  = (float*)d_ws;   // [0..4095]: per-row mean-BCE

  supcon_fused<<<dim3(HALF), dim3(THREADS), 0, stream>>>(feat, proto, lab, ws);
  supcon_reduce<<<dim3(1), dim3(THREADS), 0, stream>>>(ws, out);
}